// Round 2
// baseline (102.836 us; speedup 1.0000x reference)
//
#include <hip/hip_runtime.h>
#include <math.h>

#define QUBITS 8
#define EMBED 512
#define FFN 2048
#define ROWS_PER_BLOCK 32
#define THREADS 256

using f32x4 = __attribute__((ext_vector_type(4))) float;

// Each block: 32 rows x 2048 features. Thread t owns f = 4*t + 1024*k, k in {0,1}.
// z (cos(x)*cos(p)) computed once per (row,q) into LDS; W/bias register-resident.
__global__ __launch_bounds__(THREADS) void qff_kernel(
    const float* __restrict__ x, const float* __restrict__ params,
    const float* __restrict__ W, const float* __restrict__ b,
    float* __restrict__ out)
{
    __shared__ float z_lds[ROWS_PER_BLOCK][QUBITS];

    const int t = threadIdx.x;
    const long long row0 = (long long)blockIdx.x * ROWS_PER_BLOCK;

    // Stage z: thread t -> row t/8, qubit t%8. 256 cos total per block.
    {
        const int r = t >> 3, q = t & 7;
        const float xv = x[(row0 + r) * EMBED + q];
        const float cp = cosf(params[q * 3]);   // params[q][0], row-major [8,3]
        z_lds[r][q] = cosf(xv) * cp;
    }
    __syncthreads();

    // Register-resident W rows + bias for this thread's 8 features.
    float w[2][4][QUBITS];
    float bias[2][4];
    #pragma unroll
    for (int k = 0; k < 2; ++k) {
        const int fbase = k * 1024 + t * 4;
        #pragma unroll
        for (int j = 0; j < 4; ++j) {
            const f32x4* wp = (const f32x4*)(W + (size_t)(fbase + j) * QUBITS);
            const f32x4 w0 = wp[0], w1 = wp[1];
            w[k][j][0] = w0.x; w[k][j][1] = w0.y; w[k][j][2] = w0.z; w[k][j][3] = w0.w;
            w[k][j][4] = w1.x; w[k][j][5] = w1.y; w[k][j][6] = w1.z; w[k][j][7] = w1.w;
            bias[k][j] = b[fbase + j];
        }
    }

    for (int r = 0; r < ROWS_PER_BLOCK; ++r) {
        float z[QUBITS];
        #pragma unroll
        for (int q = 0; q < QUBITS; ++q) z[q] = z_lds[r][q];  // LDS broadcast, no conflict

        const long long orow = (row0 + r) * FFN;
        #pragma unroll
        for (int k = 0; k < 2; ++k) {
            float a[4];
            #pragma unroll
            for (int j = 0; j < 4; ++j) {
                float s = bias[k][j];
                #pragma unroll
                for (int q = 0; q < QUBITS; ++q) s = fmaf(z[q], w[k][j][q], s);
                a[j] = s;
            }
            f32x4 acc;
            acc.x = a[0]; acc.y = a[1]; acc.z = a[2]; acc.w = a[3];
            __builtin_nontemporal_store(acc, (f32x4*)(out + orow + (size_t)k * 1024 + (size_t)t * 4));
        }
    }
}

extern "C" void kernel_launch(void* const* d_in, const int* in_sizes, int n_in,
                              void* d_out, int out_size, void* d_ws, size_t ws_size,
                              hipStream_t stream) {
    const float* x      = (const float*)d_in[0];
    const float* params = (const float*)d_in[1];
    const float* W      = (const float*)d_in[2];
    const float* b      = (const float*)d_in[3];
    float* out = (float*)d_out;

    const long long rows = (long long)in_sizes[0] / EMBED;   // 65536
    const int grid = (int)(rows / ROWS_PER_BLOCK);            // 2048

    qff_kernel<<<grid, THREADS, 0, stream>>>(x, params, W, b, out);
}